// Round 19
// baseline (86.272 us; speedup 1.0000x reference)
//
#include <hip/hip_runtime.h>

#define PRESCALE 2.8853900817779268f   // 2*log2(e): exp2(PRESCALE*x) == e^{2x}

typedef short s16;
typedef unsigned short u16;
typedef unsigned int u32;
typedef __attribute__((ext_vector_type(8))) short short8v;  // 8 bf16 (4 VGPRs)
typedef __attribute__((ext_vector_type(4))) float f4;

#if __has_builtin(__builtin_amdgcn_exp2f)
#define EXP2(x) __builtin_amdgcn_exp2f(x)
#else
static __device__ inline float exp2_raw(float x){ float r; asm("v_exp_f32 %0, %1":"=v"(r):"v"(x)); return r; }
#define EXP2(x) exp2_raw(x)
#endif
#if __has_builtin(__builtin_amdgcn_rcpf)
#define RCP(x) __builtin_amdgcn_rcpf(x)
#else
static __device__ inline float rcp_raw(float x){ float r; asm("v_rcp_f32 %0, %1":"=v"(r):"v"(x)); return r; }
#define RCP(x) rcp_raw(x)
#endif

// 2 f32 -> packed bf16 (lo = first operand), RNE. Verified correct in R14.
__device__ inline u32 cvt2(float lo, float hi){
  u32 r; asm("v_cvt_pk_bf16_f32 %0, %1, %2" : "=v"(r) : "v"(lo), "v"(hi)); return r;
}
__device__ inline u16 f2bf(float f){
  union{u32 i; float f;} v; v.f = f;
  u32 r = v.i + 0x7fffu + ((v.i >> 16) & 1u);
  return (u16)(r >> 16);
}
__device__ inline f4 ldf4(const float* p){ return *reinterpret_cast<const f4*>(p); }
__device__ inline short8v cvt8(f4 a, f4 b){
  union { u32 u[4]; short8v s; } x;
  x.u[0] = cvt2(a.x, a.y); x.u[1] = cvt2(a.z, a.w);
  x.u[2] = cvt2(b.x, b.y); x.u[3] = cvt2(b.z, b.w);
  return x.s;
}

#define LP 72   // limg row pitch (u16): 144 B = 16B-aligned, 2-way banks (free)

// ================ K0 "front4": 3-node pipeline's front. 224 blocks.
//  bx < 32  : type A — img tile 64r x 64e (e-slice eg=bx&7) AND its e-slice
//             partial of AI: AIp[eg][64r][512h] = img_tile @ W_ai[:,eslice]^T
//             (K=64, block-local LDS img -> NO k_ai node, no race).
//  bx < 160 : type B — AWT4[h][t] = (E @ W_aw^T + b_aw)*PRESCALE (R15-exact).
//  else     : type C — out[:,512:] = E (f32 copy), 16 t per block.
__global__ __launch_bounds__(256) void k_front4(
    const int* __restrict__ question, const float* __restrict__ img_feat,
    const float* __restrict__ emb,
    const float* __restrict__ W_img, const float* __restrict__ b_img,
    const float* __restrict__ W_ai,  const float* __restrict__ W_aw,
    const float* __restrict__ b_aw,
    float* __restrict__ img, float* __restrict__ AIp, float* __restrict__ AWT4,
    float* __restrict__ out){
  __shared__ u16 limg[64*LP];
  const int tid = threadIdx.x, w = tid>>6, l = tid&63;
  const int lr = l & 15, lg = l >> 4;

  if (blockIdx.x < 32){
    // ---------- type A ----------
    const int r0 = (blockIdx.x >> 3)*64;    // 0,64,128,192 (rows>=196 garbage)
    const int eg = blockIdx.x & 7;          // e-slice group
    const int n0g = eg*64;                  // global e base
    const int m0 = (w>>1)*32, n0 = (w&1)*32;
    {
      // GEMM1: img[64 x 64] = relu(img_feat @ W_img^T + b), K=512.
      const float* pa0 = img_feat + (size_t)min(r0+m0+lr,    195)*512 + lg*8;
      const float* pa1 = img_feat + (size_t)min(r0+m0+16+lr, 195)*512 + lg*8;
      const float* pb0 = W_img + (size_t)(n0g + n0 + lr)*512 + lg*8;
      const float* pb1 = pb0 + (size_t)16*512;
      f4 acc[2][2] = {};
      for (int ks = 0; ks < 16; ++ks){
        const int o = ks*32;
        short8v a0 = cvt8(ldf4(pa0+o), ldf4(pa0+o+4));
        short8v a1 = cvt8(ldf4(pa1+o), ldf4(pa1+o+4));
        short8v b0 = cvt8(ldf4(pb0+o), ldf4(pb0+o+4));
        short8v b1 = cvt8(ldf4(pb1+o), ldf4(pb1+o+4));
        acc[0][0] = __builtin_amdgcn_mfma_f32_16x16x32_bf16(a0, b0, acc[0][0], 0, 0, 0);
        acc[0][1] = __builtin_amdgcn_mfma_f32_16x16x32_bf16(a0, b1, acc[0][1], 0, 0, 0);
        acc[1][0] = __builtin_amdgcn_mfma_f32_16x16x32_bf16(a1, b0, acc[1][0], 0, 0, 0);
        acc[1][1] = __builtin_amdgcn_mfma_f32_16x16x32_bf16(a1, b1, acc[1][1], 0, 0, 0);
      }
      #pragma unroll
      for (int i = 0; i < 2; ++i)
        #pragma unroll
        for (int j = 0; j < 2; ++j){
          const int el = n0 + j*16 + lr;
          const float bc = b_img[n0g + el];
          #pragma unroll
          for (int p = 0; p < 4; ++p){
            const int rl = m0 + i*16 + lg*4 + p;
            float v = fmaxf(acc[i][j][p] + bc, 0.f);
            img[(size_t)(r0+rl)*512 + n0g + el] = v;
            limg[rl*LP + el] = f2bf(v);
          }
        }
    }
    __syncthreads();
    // GEMM2: AIp[eg][64r][512h] partial, K=64 (this block's e-slice).
    // A = limg (bf16), B = W_ai[h][eslice] cvt'd. Wave w owns h-range w*128.
    const int h0w = w*128;
    #pragma unroll
    for (int rsub = 0; rsub < 4; ++rsub){
      f4 acc2[8] = {};
      #pragma unroll
      for (int ks = 0; ks < 2; ++ks){
        short8v a = *reinterpret_cast<const short8v*>(
            &limg[(rsub*16 + lr)*LP + ks*32 + lg*8]);
        #pragma unroll
        for (int nf = 0; nf < 8; ++nf){
          const float* pbn = W_ai + (size_t)(h0w + nf*16 + lr)*512 + n0g + ks*32 + lg*8;
          short8v b = cvt8(ldf4(pbn), ldf4(pbn + 4));
          acc2[nf] = __builtin_amdgcn_mfma_f32_16x16x32_bf16(a, b, acc2[nf], 0, 0, 0);
        }
      }
      #pragma unroll
      for (int nf = 0; nf < 8; ++nf)
        #pragma unroll
        for (int p = 0; p < 4; ++p)
          AIp[((size_t)eg<<17) + (size_t)(r0 + rsub*16 + lg*4 + p)*512
              + h0w + nf*16 + lr] = acc2[nf][p] * PRESCALE;
    }
  } else if (blockIdx.x < 160){
    // ---------- type B (R15-exact) ----------
    const int blk = blockIdx.x - 32;
    const int m0 = (blk >> 4)*64 + (w>>1)*32;     // h
    const int n0 = (blk & 15)*64 + (w&1)*32;      // t
    const int q0 = question[n0 + lr], q1 = question[n0 + 16 + lr];
    const float* pa0 = W_aw + (size_t)(m0 + lr)*512 + lg*8;
    const float* pa1 = pa0 + (size_t)16*512;
    const float* pe0 = emb + (size_t)q0*512 + lg*8;
    const float* pe1 = emb + (size_t)q1*512 + lg*8;
    f4 acc[2][2] = {};
    for (int ks = 0; ks < 16; ++ks){
      const int o = ks*32;
      short8v a0 = cvt8(ldf4(pa0+o), ldf4(pa0+o+4));
      short8v a1 = cvt8(ldf4(pa1+o), ldf4(pa1+o+4));
      short8v b0 = cvt8(ldf4(pe0+o), ldf4(pe0+o+4));
      short8v b1 = cvt8(ldf4(pe1+o), ldf4(pe1+o+4));
      acc[0][0] = __builtin_amdgcn_mfma_f32_16x16x32_bf16(a0, b0, acc[0][0], 0, 0, 0);
      acc[0][1] = __builtin_amdgcn_mfma_f32_16x16x32_bf16(a0, b1, acc[0][1], 0, 0, 0);
      acc[1][0] = __builtin_amdgcn_mfma_f32_16x16x32_bf16(a1, b0, acc[1][0], 0, 0, 0);
      acc[1][1] = __builtin_amdgcn_mfma_f32_16x16x32_bf16(a1, b1, acc[1][1], 0, 0, 0);
    }
    #pragma unroll
    for (int i = 0; i < 2; ++i){
      const int mb = m0 + i*16 + lg*4;            // h = mb+p, mb%4==0
      #pragma unroll
      for (int j = 0; j < 2; ++j){
        const int nn = n0 + j*16 + lr;
        f4 o;
        #pragma unroll
        for (int p = 0; p < 4; ++p)
          o[p] = (acc[i][j][p] + b_aw[mb+p]) * PRESCALE;
        *reinterpret_cast<f4*>(AWT4 + (size_t)(mb>>2)*4096 + nn*4) = o;
      }
    }
  } else {
    // ---------- type C: out[:,512:] = emb[question] (f32), 16 t/block ----------
    const int t = (blockIdx.x - 160)*16 + (tid >> 4);
    const int c0 = (tid & 15)*32;
    const float* er = emb + (size_t)question[t]*512 + c0;
    float* orow = out + (size_t)t*1024 + 512 + c0;
    #pragma unroll
    for (int qd = 0; qd < 8; ++qd)
      *reinterpret_cast<f4*>(orow + qd*4) = ldf4(er + qd*4);
  }
}

// ================ K1: score (R10-verified shape). grid(40,8,2) x 512 thr.
// Staging sums the 8 AI e-slice partials. aw[h][t] per-lane in registers.
#define RB5 5
__global__ __launch_bounds__(512) void k_score(
    const float* __restrict__ AIp, const float* __restrict__ AWT4,
    const float* __restrict__ w_att, float* __restrict__ STp){
  __shared__ float ais[RB5][64];
  __shared__ float wsh[64];
  const int tid = threadIdx.x, w = tid>>6, l = tid&63;
  const int rr = blockIdx.x, hc = blockIdx.y, th = blockIdx.z;
  const int r0 = rr*RB5, h0 = hc*64;
  if (tid < 80){                      // stage 5x64 AI tile = sum of 8 partials
    const int i = tid >> 4, j = tid & 15;
    const int r = min(r0 + i, 195);
    f4 s = ldf4(AIp + (size_t)r*512 + h0 + j*4);
    #pragma unroll
    for (int kc = 1; kc < 8; ++kc)
      s += ldf4(AIp + ((size_t)kc<<17) + (size_t)r*512 + h0 + j*4);
    *reinterpret_cast<f4*>(&ais[i][j*4]) = s;
  } else if (tid < 96){               // stage w_att chunk
    const int j = tid - 80;
    *reinterpret_cast<f4*>(&wsh[j*4]) =
        *reinterpret_cast<const f4*>(w_att + h0 + j*4);
  }
  const int t = th*512 + w*64 + l;
  const int hg0 = hc*16;
  f4 awr[16];                         // aw[h][t] for the 64-h chunk, per-lane
  #pragma unroll
  for (int j = 0; j < 16; ++j)
    awr[j] = *reinterpret_cast<const f4*>(AWT4 + (size_t)(hg0+j)*4096 + t*4);
  __syncthreads();
  #pragma unroll
  for (int i = 0; i < RB5; ++i){
    const int r = r0 + i;
    if (r >= 196) break;
    float a0=0.f, a1=0.f, a2=0.f, a3=0.f;
    #pragma unroll
    for (int j = 0; j < 16; ++j){
      f4 av = *reinterpret_cast<const f4*>(&ais[i][j*4]);
      f4 wv = *reinterpret_cast<const f4*>(&wsh[j*4]);
      a0 += wv.x*RCP(EXP2(av.x+awr[j].x)+1.f);
      a1 += wv.y*RCP(EXP2(av.y+awr[j].y)+1.f);
      a2 += wv.z*RCP(EXP2(av.z+awr[j].z)+1.f);
      a3 += wv.w*RCP(EXP2(av.w+awr[j].w)+1.f);
    }
    STp[((size_t)hc<<18) + (size_t)r*1024 + t] = (a0+a1)+(a2+a3);
  }
}

// ================ K2: no-max softmax + ctx (R17-verified).
// |score| <= sum|w_att| ~ 18 => exp2(-PRESCALE*s) cannot overflow f32.
__global__ __launch_bounds__(256) void k_ctx(
    const float* __restrict__ STp, const float* __restrict__ img,
    float* __restrict__ out){
  __shared__ float wgt[196][16];
  __shared__ float red[16][16];
  const int tid = threadIdx.x;
  const int t0 = blockIdx.x*16, e0 = blockIdx.y*64;
  const int rs = tid>>4, tl = tid&15;

  float sum = 0.f;
  for (int k = 0; k < 13; ++k){
    const int r = rs + 16*k;
    if (r < 196){
      float s = 0.f;
      #pragma unroll
      for (int c = 0; c < 8; ++c)
        s += STp[((size_t)c<<18) + (size_t)r*1024 + t0 + tl];
      float p = EXP2(-PRESCALE * s);     // softmax numerator of logit -2s
      wgt[r][tl] = p;
      sum += p;
    }
  }
  red[rs][tl] = sum;
  __syncthreads();
  if (tid < 16){
    float ss = 0.f;
    #pragma unroll
    for (int i = 0; i < 16; ++i) ss += red[i][tid];
    red[0][tid] = 1.f / (ss * 196.f);
  }
  __syncthreads();
  const float inv = red[0][tl];
  for (int k = 0; k < 13; ++k){
    const int r = rs + 16*k;
    if (r < 196) wgt[r][tl] *= inv;
  }
  __syncthreads();

  const int e = e0 + (tid & 63), tq = tid >> 6;
  float acc[4] = {0.f, 0.f, 0.f, 0.f};
  const float* ip = img + e;
  #pragma unroll 4
  for (int r = 0; r < 196; ++r){
    const float f = ip[(size_t)r*512];
    float4 w4 = *reinterpret_cast<const float4*>(&wgt[r][tq*4]);
    acc[0] += w4.x*f; acc[1] += w4.y*f; acc[2] += w4.z*f; acc[3] += w4.w*f;
  }
  #pragma unroll
  for (int j = 0; j < 4; ++j)
    out[(size_t)(t0 + tq*4 + j)*1024 + e] = acc[j];
}

extern "C" void kernel_launch(void* const* d_in, const int* in_sizes, int n_in,
                              void* d_out, int out_size, void* d_ws, size_t ws_size,
                              hipStream_t stream) {
  const int*   question = (const int*)d_in[0];
  const float* img_feat = (const float*)d_in[1];
  const float* emb      = (const float*)d_in[2];
  const float* W_img    = (const float*)d_in[3];
  const float* b_img    = (const float*)d_in[4];
  const float* W_ai     = (const float*)d_in[5];
  const float* W_aw     = (const float*)d_in[6];
  const float* b_aw     = (const float*)d_in[7];
  const float* w_att    = (const float*)d_in[8];
  // d_in[9] = b_att: constant pre-softmax shift -> cancels in softmax.
  float* out = (float*)d_out;

  char* ws = (char*)d_ws;
  float* img   = (float*)(ws);                // 256x512 f32     = 524288 B
  float* AIp   = (float*)(ws + 524288);       // 8x256x512 f32   = 4194304 B
  float* AWT4  = (float*)(ws + 4718592);      // 128x1024x4 f32  = 2097152 B
  float* STp   = (float*)(ws + 6815744);      // 8x256x1024 f32  = 8388608 B

  hipLaunchKernelGGL(k_front4, dim3(224),    dim3(256), 0, stream,
                     question, img_feat, emb, W_img, b_img, W_ai, W_aw, b_aw,
                     img, AIp, AWT4, out);
  hipLaunchKernelGGL(k_score,  dim3(40,8,2), dim3(512), 0, stream,
                     AIp, AWT4, w_att, STp);
  hipLaunchKernelGGL(k_ctx,    dim3(64,8),   dim3(256), 0, stream, STp, img, out);
}

// Round 20
// 76.266 us; speedup vs baseline: 1.1312x; 1.1312x over previous
//
#include <hip/hip_runtime.h>

#define PRESCALE 2.8853900817779268f   // 2*log2(e): exp2(PRESCALE*x) == e^{2x}

typedef short s16;
typedef unsigned short u16;
typedef unsigned int u32;
typedef __attribute__((ext_vector_type(8))) short short8v;  // 8 bf16 (4 VGPRs)
typedef __attribute__((ext_vector_type(4))) float f4;

#if __has_builtin(__builtin_amdgcn_exp2f)
#define EXP2(x) __builtin_amdgcn_exp2f(x)
#else
static __device__ inline float exp2_raw(float x){ float r; asm("v_exp_f32 %0, %1":"=v"(r):"v"(x)); return r; }
#define EXP2(x) exp2_raw(x)
#endif
#if __has_builtin(__builtin_amdgcn_rcpf)
#define RCP(x) __builtin_amdgcn_rcpf(x)
#else
static __device__ inline float rcp_raw(float x){ float r; asm("v_rcp_f32 %0, %1":"=v"(r):"v"(x)); return r; }
#define RCP(x) rcp_raw(x)
#endif

// 2 f32 -> packed bf16 (lo = first operand), RNE. Verified correct in R14.
__device__ inline u32 cvt2(float lo, float hi){
  u32 r; asm("v_cvt_pk_bf16_f32 %0, %1, %2" : "=v"(r) : "v"(lo), "v"(hi)); return r;
}
__device__ inline f4 ldf4(const float* p){ return *reinterpret_cast<const f4*>(p); }
__device__ inline short8v cvt8(f4 a, f4 b){
  union { u32 u[4]; short8v s; } x;
  x.u[0] = cvt2(a.x, a.y); x.u[1] = cvt2(a.z, a.w);
  x.u[2] = cvt2(b.x, b.y); x.u[3] = cvt2(b.z, b.w);
  return x.s;
}

// ================ K0 "front2" (R15/R17-exact, best verified): img GEMM
// (32 blk) + AWT GEMM (128 blk) + E copy (64 blk). Operands cvt'd f32->bf16
// in registers; no LDS. R16/R18/R19 lessons: every restructure regressed.
__global__ __launch_bounds__(256) void k_front2(
    const int* __restrict__ question, const float* __restrict__ img_feat,
    const float* __restrict__ emb,
    const float* __restrict__ W_img, const float* __restrict__ b_img,
    const float* __restrict__ W_aw,  const float* __restrict__ b_aw,
    float* __restrict__ img, float* __restrict__ AWT4, float* __restrict__ out){
  const int tid = threadIdx.x, w = tid>>6, l = tid&63;
  const int lr = l & 15, lg = l >> 4;

  if (blockIdx.x < 32){
    // ---- img[r][e] = relu(img_feat @ W_img^T + b). 64x64 tile per block.
    const int m0 = (blockIdx.x >> 3)*64 + (w>>1)*32;   // r (rows >=196: clamped dup)
    const int n0 = (blockIdx.x & 7)*64 + (w&1)*32;     // e
    const float* pa0 = img_feat + (size_t)min(m0+lr,    195)*512 + lg*8;
    const float* pa1 = img_feat + (size_t)min(m0+16+lr, 195)*512 + lg*8;
    const float* pb0 = W_img + (size_t)(n0 + lr)*512 + lg*8;
    const float* pb1 = pb0 + (size_t)16*512;
    f4 acc[2][2] = {};
    for (int ks = 0; ks < 16; ++ks){
      const int o = ks*32;
      short8v a0 = cvt8(ldf4(pa0+o), ldf4(pa0+o+4));
      short8v a1 = cvt8(ldf4(pa1+o), ldf4(pa1+o+4));
      short8v b0 = cvt8(ldf4(pb0+o), ldf4(pb0+o+4));
      short8v b1 = cvt8(ldf4(pb1+o), ldf4(pb1+o+4));
      acc[0][0] = __builtin_amdgcn_mfma_f32_16x16x32_bf16(a0, b0, acc[0][0], 0, 0, 0);
      acc[0][1] = __builtin_amdgcn_mfma_f32_16x16x32_bf16(a0, b1, acc[0][1], 0, 0, 0);
      acc[1][0] = __builtin_amdgcn_mfma_f32_16x16x32_bf16(a1, b0, acc[1][0], 0, 0, 0);
      acc[1][1] = __builtin_amdgcn_mfma_f32_16x16x32_bf16(a1, b1, acc[1][1], 0, 0, 0);
    }
    #pragma unroll
    for (int i = 0; i < 2; ++i)
      #pragma unroll
      for (int j = 0; j < 2; ++j){
        const int nn = n0 + j*16 + lr;
        const float bc = b_img[nn];
        #pragma unroll
        for (int p = 0; p < 4; ++p){
          const int mm = m0 + i*16 + lg*4 + p;
          img[(size_t)mm*512 + nn] = fmaxf(acc[i][j][p] + bc, 0.f);
        }
      }
  } else if (blockIdx.x < 160){
    // ---- AWT4[h][t] = (E @ W_aw^T + b_aw)*PRESCALE, E gathered per-lane.
    const int blk = blockIdx.x - 32;
    const int m0 = (blk >> 4)*64 + (w>>1)*32;     // h
    const int n0 = (blk & 15)*64 + (w&1)*32;      // t
    const int q0 = question[n0 + lr], q1 = question[n0 + 16 + lr];
    const float* pa0 = W_aw + (size_t)(m0 + lr)*512 + lg*8;
    const float* pa1 = pa0 + (size_t)16*512;
    const float* pe0 = emb + (size_t)q0*512 + lg*8;
    const float* pe1 = emb + (size_t)q1*512 + lg*8;
    f4 acc[2][2] = {};
    for (int ks = 0; ks < 16; ++ks){
      const int o = ks*32;
      short8v a0 = cvt8(ldf4(pa0+o), ldf4(pa0+o+4));
      short8v a1 = cvt8(ldf4(pa1+o), ldf4(pa1+o+4));
      short8v b0 = cvt8(ldf4(pe0+o), ldf4(pe0+o+4));
      short8v b1 = cvt8(ldf4(pe1+o), ldf4(pe1+o+4));
      acc[0][0] = __builtin_amdgcn_mfma_f32_16x16x32_bf16(a0, b0, acc[0][0], 0, 0, 0);
      acc[0][1] = __builtin_amdgcn_mfma_f32_16x16x32_bf16(a0, b1, acc[0][1], 0, 0, 0);
      acc[1][0] = __builtin_amdgcn_mfma_f32_16x16x32_bf16(a1, b0, acc[1][0], 0, 0, 0);
      acc[1][1] = __builtin_amdgcn_mfma_f32_16x16x32_bf16(a1, b1, acc[1][1], 0, 0, 0);
    }
    #pragma unroll
    for (int i = 0; i < 2; ++i){
      const int mb = m0 + i*16 + lg*4;            // h = mb+p, mb%4==0
      #pragma unroll
      for (int j = 0; j < 2; ++j){
        const int nn = n0 + j*16 + lr;
        f4 o;
        #pragma unroll
        for (int p = 0; p < 4; ++p)
          o[p] = (acc[i][j][p] + b_aw[mb+p]) * PRESCALE;
        *reinterpret_cast<f4*>(AWT4 + (size_t)(mb>>2)*4096 + nn*4) = o;
      }
    }
  } else {
    // ---- out[:,512:] = emb[question] (f32), 16 t per block.
    const int t = (blockIdx.x - 160)*16 + (tid >> 4);
    const int c0 = (tid & 15)*32;
    const float* er = emb + (size_t)question[t]*512 + c0;
    float* orow = out + (size_t)t*1024 + 512 + c0;
    #pragma unroll
    for (int qd = 0; qd < 8; ++qd)
      *reinterpret_cast<f4*>(orow + qd*4) = ldf4(er + qd*4);
  }
}

// ================ K1: AI partials, split-K x4 (R15-exact). grid(32,4).
__global__ __launch_bounds__(256) void k_ai(
    const float* __restrict__ img, const float* __restrict__ W_ai,
    float* __restrict__ AIp){
  const int tid = threadIdx.x, w = tid>>6, l = tid&63;
  const int lr = l & 15, lg = l >> 4;
  const int m0 = (blockIdx.x >> 3)*64 + (w>>1)*32;   // r
  const int n0 = (blockIdx.x & 7)*64 + (w&1)*32;     // h
  const int k0 = blockIdx.y*128;
  const float* pa0 = img  + (size_t)(m0 + lr)*512 + k0 + lg*8;
  const float* pa1 = pa0 + (size_t)16*512;
  const float* pb0 = W_ai + (size_t)(n0 + lr)*512 + k0 + lg*8;
  const float* pb1 = pb0 + (size_t)16*512;
  f4 acc[2][2] = {};
  #pragma unroll
  for (int ks = 0; ks < 4; ++ks){
    const int o = ks*32;
    short8v a0 = cvt8(ldf4(pa0+o), ldf4(pa0+o+4));
    short8v a1 = cvt8(ldf4(pa1+o), ldf4(pa1+o+4));
    short8v b0 = cvt8(ldf4(pb0+o), ldf4(pb0+o+4));
    short8v b1 = cvt8(ldf4(pb1+o), ldf4(pb1+o+4));
    acc[0][0] = __builtin_amdgcn_mfma_f32_16x16x32_bf16(a0, b0, acc[0][0], 0, 0, 0);
    acc[0][1] = __builtin_amdgcn_mfma_f32_16x16x32_bf16(a0, b1, acc[0][1], 0, 0, 0);
    acc[1][0] = __builtin_amdgcn_mfma_f32_16x16x32_bf16(a1, b0, acc[1][0], 0, 0, 0);
    acc[1][1] = __builtin_amdgcn_mfma_f32_16x16x32_bf16(a1, b1, acc[1][1], 0, 0, 0);
  }
  #pragma unroll
  for (int i = 0; i < 2; ++i)
    #pragma unroll
    for (int j = 0; j < 2; ++j){
      const int nn = n0 + j*16 + lr;
      #pragma unroll
      for (int p = 0; p < 4; ++p){
        const int mm = m0 + i*16 + lg*4 + p;
        AIp[((size_t)blockIdx.y<<17) + (size_t)mm*512 + nn] = acc[i][j][p] * PRESCALE;
      }
    }
}

// ================ K2: score (R10-verified shape, R15-exact). grid(40,8,2).
#define RB5 5
__global__ __launch_bounds__(512) void k_score(
    const float* __restrict__ AIp, const float* __restrict__ AWT4,
    const float* __restrict__ w_att, float* __restrict__ STp){
  __shared__ float ais[RB5][64];
  __shared__ float wsh[64];
  const int tid = threadIdx.x, w = tid>>6, l = tid&63;
  const int rr = blockIdx.x, hc = blockIdx.y, th = blockIdx.z;
  const int r0 = rr*RB5, h0 = hc*64;
  if (tid < 80){                      // stage 5x64 AI tile = sum of 4 partials
    const int i = tid >> 4, j = tid & 15;
    const int r = min(r0 + i, 195);
    f4 s = ldf4(AIp + (size_t)r*512 + h0 + j*4);
    #pragma unroll
    for (int kc = 1; kc < 4; ++kc)
      s += ldf4(AIp + ((size_t)kc<<17) + (size_t)r*512 + h0 + j*4);
    *reinterpret_cast<f4*>(&ais[i][j*4]) = s;
  } else if (tid < 96){               // stage w_att chunk
    const int j = tid - 80;
    *reinterpret_cast<f4*>(&wsh[j*4]) =
        *reinterpret_cast<const f4*>(w_att + h0 + j*4);
  }
  const int t = th*512 + w*64 + l;
  const int hg0 = hc*16;
  f4 awr[16];                         // aw[h][t] for the 64-h chunk, per-lane
  #pragma unroll
  for (int j = 0; j < 16; ++j)
    awr[j] = *reinterpret_cast<const f4*>(AWT4 + (size_t)(hg0+j)*4096 + t*4);
  __syncthreads();
  #pragma unroll
  for (int i = 0; i < RB5; ++i){
    const int r = r0 + i;
    if (r >= 196) break;
    float a0=0.f, a1=0.f, a2=0.f, a3=0.f;
    #pragma unroll
    for (int j = 0; j < 16; ++j){
      f4 av = *reinterpret_cast<const f4*>(&ais[i][j*4]);
      f4 wv = *reinterpret_cast<const f4*>(&wsh[j*4]);
      a0 += wv.x*RCP(EXP2(av.x+awr[j].x)+1.f);
      a1 += wv.y*RCP(EXP2(av.y+awr[j].y)+1.f);
      a2 += wv.z*RCP(EXP2(av.z+awr[j].z)+1.f);
      a3 += wv.w*RCP(EXP2(av.w+awr[j].w)+1.f);
    }
    STp[((size_t)hc<<18) + (size_t)r*1024 + t] = (a0+a1)+(a2+a3);
  }
}

// ================ K3: no-max softmax + ctx (R17-verified).
// |score| <= sum|w_att| ~ 18 => exp2(-PRESCALE*s) cannot overflow f32.
__global__ __launch_bounds__(256) void k_ctx(
    const float* __restrict__ STp, const float* __restrict__ img,
    float* __restrict__ out){
  __shared__ float wgt[196][16];
  __shared__ float red[16][16];
  const int tid = threadIdx.x;
  const int t0 = blockIdx.x*16, e0 = blockIdx.y*64;
  const int rs = tid>>4, tl = tid&15;

  float sum = 0.f;
  for (int k = 0; k < 13; ++k){
    const int r = rs + 16*k;
    if (r < 196){
      float s = 0.f;
      #pragma unroll
      for (int c = 0; c < 8; ++c)
        s += STp[((size_t)c<<18) + (size_t)r*1024 + t0 + tl];
      float p = EXP2(-PRESCALE * s);     // softmax numerator of logit -2s
      wgt[r][tl] = p;
      sum += p;
    }
  }
  red[rs][tl] = sum;
  __syncthreads();
  if (tid < 16){
    float ss = 0.f;
    #pragma unroll
    for (int i = 0; i < 16; ++i) ss += red[i][tid];
    red[0][tid] = 1.f / (ss * 196.f);
  }
  __syncthreads();
  const float inv = red[0][tl];
  for (int k = 0; k < 13; ++k){
    const int r = rs + 16*k;
    if (r < 196) wgt[r][tl] *= inv;
  }
  __syncthreads();

  const int e = e0 + (tid & 63), tq = tid >> 6;
  float acc[4] = {0.f, 0.f, 0.f, 0.f};
  const float* ip = img + e;
  #pragma unroll 4
  for (int r = 0; r < 196; ++r){
    const float f = ip[(size_t)r*512];
    float4 w4 = *reinterpret_cast<const float4*>(&wgt[r][tq*4]);
    acc[0] += w4.x*f; acc[1] += w4.y*f; acc[2] += w4.z*f; acc[3] += w4.w*f;
  }
  #pragma unroll
  for (int j = 0; j < 4; ++j)
    out[(size_t)(t0 + tq*4 + j)*1024 + e] = acc[j];
}

extern "C" void kernel_launch(void* const* d_in, const int* in_sizes, int n_in,
                              void* d_out, int out_size, void* d_ws, size_t ws_size,
                              hipStream_t stream) {
  const int*   question = (const int*)d_in[0];
  const float* img_feat = (const float*)d_in[1];
  const float* emb      = (const float*)d_in[2];
  const float* W_img    = (const float*)d_in[3];
  const float* b_img    = (const float*)d_in[4];
  const float* W_ai     = (const float*)d_in[5];
  const float* W_aw     = (const float*)d_in[6];
  const float* b_aw     = (const float*)d_in[7];
  const float* w_att    = (const float*)d_in[8];
  // d_in[9] = b_att: constant pre-softmax shift -> cancels in softmax.
  float* out = (float*)d_out;

  char* ws = (char*)d_ws;
  float* img   = (float*)(ws);                // 256x512 f32    = 524288 B
  float* AIp   = (float*)(ws + 524288);       // 4x256x512 f32  = 2097152 B
  float* AWT4  = (float*)(ws + 2621440);      // 128x1024x4 f32 = 2097152 B
  float* STp   = (float*)(ws + 4718592);      // 8x256x1024 f32 = 8388608 B

  hipLaunchKernelGGL(k_front2, dim3(224),    dim3(256), 0, stream,
                     question, img_feat, emb, W_img, b_img, W_aw, b_aw,
                     img, AWT4, out);
  hipLaunchKernelGGL(k_ai,     dim3(32,4),   dim3(256), 0, stream,
                     img, W_ai, AIp);
  hipLaunchKernelGGL(k_score,  dim3(40,8,2), dim3(512), 0, stream,
                     AIp, AWT4, w_att, STp);
  hipLaunchKernelGGL(k_ctx,    dim3(64,8),   dim3(256), 0, stream, STp, img, out);
}